// Round 7
// baseline (825.103 us; speedup 1.0000x reference)
//
#include <hip/hip_runtime.h>
#include <hip/hip_fp16.h>

#define EPSV 1e-5f

typedef _Float16 f16;
typedef f16 half8 __attribute__((ext_vector_type(8)));
typedef float f32x4 __attribute__((ext_vector_type(4)));

// ---------------- degree / CSR construction ----------------

// deg pre-zeroed by memset; counts edges + self loops in one pass
__global__ void k_count(const int* __restrict__ dst, int E, int N, int* __restrict__ deg) {
    int i = blockIdx.x * blockDim.x + threadIdx.x;
    if (i >= E + N) return;
    int d = (i < E) ? dst[i] : (i - E);
    atomicAdd(&deg[d], 1);
}

__global__ void k_disqrt(const int* __restrict__ deg, float* __restrict__ disq, int N) {
    int n = blockIdx.x * blockDim.x + threadIdx.x;
    if (n < N) disq[n] = rsqrtf((float)deg[n]);
}

__global__ void k_scan1(const int* __restrict__ deg, int N,
                        int* __restrict__ incl, int* __restrict__ bsum) {
    __shared__ int s[256];
    int n = blockIdx.x * 256 + threadIdx.x;
    s[threadIdx.x] = (n < N) ? deg[n] : 0;
    __syncthreads();
    for (int off = 1; off < 256; off <<= 1) {
        int v = (threadIdx.x >= off) ? s[threadIdx.x - off] : 0;
        __syncthreads();
        s[threadIdx.x] += v;
        __syncthreads();
    }
    if (n < N) incl[n] = s[threadIdx.x];
    if (threadIdx.x == 255) bsum[blockIdx.x] = s[255];
}

__global__ void k_scan2(const int* __restrict__ bsum, int NB, int* __restrict__ boff) {
    if (blockIdx.x == 0 && threadIdx.x == 0) {
        int run = 0;
        for (int b = 0; b < NB; ++b) { boff[b] = run; run += bsum[b]; }
    }
}

__global__ void k_scan3(const int* __restrict__ deg, const int* __restrict__ incl,
                        const int* __restrict__ boff, int N,
                        int* __restrict__ rs, int* __restrict__ cur) {
    int n = blockIdx.x * 256 + threadIdx.x;
    if (n < N) {
        int v = incl[n] - deg[n] + boff[blockIdx.x];
        rs[n] = v;
        cur[n] = v;
    }
}

// CSR fill: one 4B scattered write per edge (src only; weight recomputed in gather)
__global__ void k_fill(const int* __restrict__ src, const int* __restrict__ dst,
                       int E, int N, int* __restrict__ cur, int* __restrict__ csr_s) {
    int i = blockIdx.x * blockDim.x + threadIdx.x;
    int total = E + N;
    if (i >= total) return;
    int s, d;
    if (i < E) { s = src[i]; d = dst[i]; }
    else       { s = i - E; d = s; }
    int slot = atomicAdd(&cur[d], 1);
    csr_s[slot] = s;
}

// ---------------- BN stats for layer 0 input x (width 7) ----------------

__global__ void k_bnstats(const float* __restrict__ H, int N, int C, int SP,
                          float* __restrict__ colsum, float* __restrict__ colsq) {
    int j = threadIdx.x;
    if (j >= C) return;
    int r0 = blockIdx.x * 256;
    int rend = r0 + 256; if (rend > N) rend = N;
    float s = 0.f, q = 0.f;
    for (int r = r0; r < rend; ++r) {
        float v = H[(size_t)r * SP + j];
        s += v;
        q += v * v;
    }
    atomicAdd(&colsum[j], s);
    atomicAdd(&colsq[j], q);
}

__global__ void k_bnfinal(const float* __restrict__ colsum, const float* __restrict__ colsq,
                          const float* __restrict__ g, const float* __restrict__ b,
                          int C, float invN,
                          float* __restrict__ scale, float* __restrict__ shift) {
    int i = threadIdx.x;
    if (i < C) {
        float m = colsum[i] * invN;
        float v = colsq[i] * invN - m * m;
        float rstd = rsqrtf(fmaxf(v, 0.f) + EPSV);
        float sc = rstd * g[i];
        scale[i] = sc;
        shift[i] = b[i] - m * sc;
    }
}

// ---- per-layer weight prep: Wp_t[n][k] = fp16(scale[k] * W[k][n]), zero-padded ----

__global__ void k_prepw(const float* __restrict__ W, const float* __restrict__ scale,
                        f16* __restrict__ Wp, int Cin, int Cout, int KP, int NP) {
    int idx = blockIdx.x * blockDim.x + threadIdx.x;
    if (idx >= NP * KP) return;
    int n = idx / KP;
    int k = idx - n * KP;
    float v = 0.f;
    if (k < Cin && n < Cout) v = scale[k] * W[(size_t)k * Cout + n];
    Wp[idx] = (f16)v;
}

__global__ void k_wrow(const float* __restrict__ W, const float* __restrict__ shift,
                       float* __restrict__ wrow, int Cin, int Cout, int NP) {
    int c = blockIdx.x * blockDim.x + threadIdx.x;
    if (c >= NP) return;
    float acc = 0.f;
    if (c < Cout)
        for (int k = 0; k < Cin; ++k) acc += shift[k] * W[(size_t)k * Cout + c];
    wrow[c] = acc;
}

// ---------------- pad x [N,7] -> xp [N,8] fp32 ----------------

__global__ void k_padx(const float* __restrict__ x, float* __restrict__ xp, int N) {
    int n = blockIdx.x * blockDim.x + threadIdx.x;
    if (n >= N) return;
    float4 a, b;
    a.x = x[(size_t)n * 7 + 0]; a.y = x[(size_t)n * 7 + 1];
    a.z = x[(size_t)n * 7 + 2]; a.w = x[(size_t)n * 7 + 3];
    b.x = x[(size_t)n * 7 + 4]; b.y = x[(size_t)n * 7 + 5];
    b.z = x[(size_t)n * 7 + 6]; b.w = 0.f;
    *(float4*)(xp + (size_t)n * 8) = a;
    *(float4*)(xp + (size_t)n * 8 + 4) = b;
}

// ---------------- gathers: G = S . X ----------------

// width-8 fp32 input; emits rsum[n] = dn * sum_e disq[s]
__global__ void k_gather8(const float* __restrict__ xp, const int* __restrict__ csr_s,
                          const float* __restrict__ disq,
                          const int* __restrict__ rs, const int* __restrict__ deg,
                          __half* __restrict__ out, float* __restrict__ rsum, int N) {
    int n = blockIdx.x * blockDim.x + threadIdx.x;
    if (n >= N) return;
    int e0 = rs[n], eend = e0 + deg[n];
    float dn = disq[n];
    float a0 = 0.f, a1 = 0.f, a2 = 0.f, a3 = 0.f, a4 = 0.f, a5 = 0.f, a6 = 0.f, a7 = 0.f;
    float ws = 0.f;
    for (int e = e0; e < eend; ++e) {
        int s = csr_s[e];
        float w = disq[s];
        ws += w;
        float4 r0 = *(const float4*)(xp + (size_t)s * 8);
        float4 r1 = *(const float4*)(xp + (size_t)s * 8 + 4);
        a0 = fmaf(w, r0.x, a0); a1 = fmaf(w, r0.y, a1);
        a2 = fmaf(w, r0.z, a2); a3 = fmaf(w, r0.w, a3);
        a4 = fmaf(w, r1.x, a4); a5 = fmaf(w, r1.y, a5);
        a6 = fmaf(w, r1.z, a6); a7 = fmaf(w, r1.w, a7);
    }
    rsum[n] = ws * dn;
    __half h[8];
    h[0] = __float2half(a0 * dn); h[1] = __float2half(a1 * dn);
    h[2] = __float2half(a2 * dn); h[3] = __float2half(a3 * dn);
    h[4] = __float2half(a4 * dn); h[5] = __float2half(a5 * dn);
    h[6] = __float2half(a6 * dn); h[7] = __float2half(a7 * dn);
    *(float4*)(out + (size_t)n * 8) = *(float4*)h;
}

// same-node edge-split gather: one wave = one node. Lanes = NG groups x CH8 lanes.
// Group g takes edges e0+g, e0+g+NG, ...; lane lsub covers halfs [lsub*8, lsub*8+8).
// Cross-group tree-reduce via shfl; group 0 writes. Zero divergence within wave.
__global__ __launch_bounds__(256) void k_gather_split(
    const __half* __restrict__ A, int SPh, int CH8, int NG,
    const int* __restrict__ rs, const int* __restrict__ deg,
    const int* __restrict__ csr_s, const float* __restrict__ disq,
    __half* __restrict__ out, int N) {
    int wave = threadIdx.x >> 6;
    int lane = threadIdx.x & 63;
    int n = blockIdx.x * 4 + wave;
    if (n >= N) return;
    int g = lane / CH8;
    int lsub = lane - g * CH8;
    int c0 = lsub * 8;
    float acc[8] = {};

    if (g < NG) {
        int e0 = rs[n];
        int eend = e0 + deg[n];
        int e = e0 + g;
        for (; e + NG < eend; e += 2 * NG) {
            int s0 = csr_s[e], s1 = csr_s[e + NG];
            float w0 = disq[s0], w1 = disq[s1];
            float4 r0 = *(const float4*)(A + (size_t)s0 * SPh + c0);
            float4 r1 = *(const float4*)(A + (size_t)s1 * SPh + c0);
            float2 q0 = __half22float2(((const __half2*)&r0)[0]);
            float2 q1 = __half22float2(((const __half2*)&r0)[1]);
            float2 q2 = __half22float2(((const __half2*)&r0)[2]);
            float2 q3 = __half22float2(((const __half2*)&r0)[3]);
            acc[0] = fmaf(w0, q0.x, acc[0]); acc[1] = fmaf(w0, q0.y, acc[1]);
            acc[2] = fmaf(w0, q1.x, acc[2]); acc[3] = fmaf(w0, q1.y, acc[3]);
            acc[4] = fmaf(w0, q2.x, acc[4]); acc[5] = fmaf(w0, q2.y, acc[5]);
            acc[6] = fmaf(w0, q3.x, acc[6]); acc[7] = fmaf(w0, q3.y, acc[7]);
            q0 = __half22float2(((const __half2*)&r1)[0]);
            q1 = __half22float2(((const __half2*)&r1)[1]);
            q2 = __half22float2(((const __half2*)&r1)[2]);
            q3 = __half22float2(((const __half2*)&r1)[3]);
            acc[0] = fmaf(w1, q0.x, acc[0]); acc[1] = fmaf(w1, q0.y, acc[1]);
            acc[2] = fmaf(w1, q1.x, acc[2]); acc[3] = fmaf(w1, q1.y, acc[3]);
            acc[4] = fmaf(w1, q2.x, acc[4]); acc[5] = fmaf(w1, q2.y, acc[5]);
            acc[6] = fmaf(w1, q3.x, acc[6]); acc[7] = fmaf(w1, q3.y, acc[7]);
        }
        if (e < eend) {
            int s0 = csr_s[e];
            float w0 = disq[s0];
            float4 r0 = *(const float4*)(A + (size_t)s0 * SPh + c0);
            float2 q0 = __half22float2(((const __half2*)&r0)[0]);
            float2 q1 = __half22float2(((const __half2*)&r0)[1]);
            float2 q2 = __half22float2(((const __half2*)&r0)[2]);
            float2 q3 = __half22float2(((const __half2*)&r0)[3]);
            acc[0] = fmaf(w0, q0.x, acc[0]); acc[1] = fmaf(w0, q0.y, acc[1]);
            acc[2] = fmaf(w0, q1.x, acc[2]); acc[3] = fmaf(w0, q1.y, acc[3]);
            acc[4] = fmaf(w0, q2.x, acc[4]); acc[5] = fmaf(w0, q2.y, acc[5]);
            acc[6] = fmaf(w0, q3.x, acc[6]); acc[7] = fmaf(w0, q3.y, acc[7]);
        }
    }

    // tree-reduce groups: g += g+off for off = pow2 halves
    int start = 1;
    while (start < NG) start <<= 1;
    for (int off = start >> 1; off > 0; off >>= 1) {
        bool take = (g + off < NG);
#pragma unroll
        for (int i = 0; i < 8; ++i) {
            float v = __shfl(acc[i], lane + off * CH8);
            if (take) acc[i] += v;
        }
    }

    if (g == 0) {
        float dn = disq[n];
        __half2 h[4];
        h[0] = __floats2half2_rn(acc[0] * dn, acc[1] * dn);
        h[1] = __floats2half2_rn(acc[2] * dn, acc[3] * dn);
        h[2] = __floats2half2_rn(acc[4] * dn, acc[5] * dn);
        h[3] = __floats2half2_rn(acc[6] * dn, acc[7] * dn);
        *(float4*)(out + (size_t)n * SPh + c0) = *(float4*)h;
    }
}

// ------------- MFMA GEMM: H = relu(G @ Wp_t^T + rsum (x) wrow + bias) -------------

__global__ __launch_bounds__(256) void k_gemm_mfma(
    const f16* __restrict__ A, int SPa,
    const f16* __restrict__ Bt, int KP,
    const float* __restrict__ rsum, const float* __restrict__ wrow,
    const float* __restrict__ bias,
    f16* __restrict__ out, int SPo,
    float* __restrict__ colsum, float* __restrict__ colsq, int do_stats,
    int N, int Cout) {
    __shared__ f16 As[128][40];
    __shared__ float s_sum[64];
    __shared__ float s_sq[64];
    const int r0 = blockIdx.x * 128;
    const int c0 = blockIdx.y * 64;
    const int t = threadIdx.x;
    const int wave = t >> 6, lane = t & 63;
    const int l15 = lane & 15, quad = lane >> 4;

    if (t < 64) { s_sum[t] = 0.f; s_sq[t] = 0.f; }

    f32x4 zero4 = {0.f, 0.f, 0.f, 0.f};
    f32x4 acc[2][4];
#pragma unroll
    for (int mi = 0; mi < 2; ++mi)
#pragma unroll
        for (int ni = 0; ni < 4; ++ni) acc[mi][ni] = zero4;

    const int KT = KP >> 5;
    for (int kt = 0; kt < KT; ++kt) {
        int k0 = kt * 32;
        {
            int kcol = (t & 7) * 4;
            int rbase = t >> 3;
            int gk = k0 + kcol;
            bool kok = (gk + 4 <= SPa);
#pragma unroll
            for (int i = 0; i < 4; ++i) {
                int row = rbase + i * 32;
                int gr = r0 + row;
                ushort4 v = {0, 0, 0, 0};
                if (gr < N && kok)
                    v = *(const ushort4*)(A + (size_t)gr * SPa + gk);
                *(ushort4*)&As[row][kcol] = v;
            }
        }
        __syncthreads();
        half8 a0 = *(const half8*)&As[wave * 32 + l15][quad * 8];
        half8 a1 = *(const half8*)&As[wave * 32 + 16 + l15][quad * 8];
#pragma unroll
        for (int ni = 0; ni < 4; ++ni) {
            half8 b = *(const half8*)(Bt + (size_t)(c0 + ni * 16 + l15) * KP + k0 + quad * 8);
            acc[0][ni] = __builtin_amdgcn_mfma_f32_16x16x32_f16(a0, b, acc[0][ni], 0, 0, 0);
            acc[1][ni] = __builtin_amdgcn_mfma_f32_16x16x32_f16(a1, b, acc[1][ni], 0, 0, 0);
        }
        __syncthreads();
    }

    float wr[4], bi[4];
#pragma unroll
    for (int ni = 0; ni < 4; ++ni) {
        int gc = c0 + ni * 16 + l15;
        wr[ni] = wrow[gc];
        bi[ni] = (gc < Cout) ? bias[gc] : 0.f;
    }
    float ps[4] = {}, pq[4] = {};
#pragma unroll
    for (int mi = 0; mi < 2; ++mi) {
#pragma unroll
        for (int reg = 0; reg < 4; ++reg) {
            int gr = r0 + wave * 32 + mi * 16 + quad * 4 + reg;
            if (gr >= N) continue;
            float rsv = rsum[gr];
#pragma unroll
            for (int ni = 0; ni < 4; ++ni) {
                int gc = c0 + ni * 16 + l15;
                float o = acc[mi][ni][reg] + rsv * wr[ni] + bi[ni];
                o = fmaxf(o, 0.f);
                if (gc >= Cout) o = 0.f;
                ps[ni] += o; pq[ni] += o * o;
                if (gc < SPo) out[(size_t)gr * SPo + gc] = (f16)o;
            }
        }
    }
    if (do_stats) {
#pragma unroll
        for (int ni = 0; ni < 4; ++ni) {
            int cl = ni * 16 + l15;
            atomicAdd(&s_sum[cl], ps[ni]);
            atomicAdd(&s_sq[cl], pq[ni]);
        }
        __syncthreads();
        if (t < 64 && c0 + t < Cout) {
            atomicAdd(&colsum[c0 + t], s_sum[t]);
            atomicAdd(&colsq[c0 + t], s_sq[t]);
        }
    }
}

// ---------------- mean pool (fp16 input, batch is sorted) ----------------

__global__ void k_pool_h(const __half* __restrict__ H, int SP, const int* __restrict__ batch,
                         int N, int C, float* __restrict__ pooled) {
    __shared__ int sb[256];
    int r0 = blockIdx.x * 256;
    int rows = N - r0; if (rows > 256) rows = 256;
    if (threadIdx.x < rows) sb[threadIdx.x] = batch[r0 + threadIdx.x];
    __syncthreads();
    int c = threadIdx.x;
    if (c >= C) return;
    int cg = sb[0];
    float acc = 0.f;
    for (int r = 0; r < rows; ++r) {
        int g = sb[r];
        if (g != cg) { atomicAdd(&pooled[cg * C + c], acc); acc = 0.f; cg = g; }
        acc += __half2float(H[(size_t)(r0 + r) * SP + c]);
    }
    atomicAdd(&pooled[cg * C + c], acc);
}

__global__ void k_bounds(const int* __restrict__ batch, int N,
                         int* __restrict__ gstart, int* __restrict__ gend) {
    int n = blockIdx.x * blockDim.x + threadIdx.x;
    if (n >= N) return;
    int g = batch[n];
    if (n == 0 || batch[n - 1] != g) gstart[g] = n;
    if (n == N - 1 || batch[n + 1] != g) gend[g] = n + 1;
}

// ---------------- head MLP ----------------

__global__ void k_mlp(const float* __restrict__ pooled, const int* __restrict__ gstart,
                      const int* __restrict__ gend,
                      const float* __restrict__ Wl1, const float* __restrict__ bl1,
                      const float* __restrict__ Wl2, const float* __restrict__ bl2,
                      float* __restrict__ out, int C) {
    __shared__ float p[199];
    __shared__ float t1[49];
    int g = blockIdx.x;
    int cnt = gend[g] - gstart[g];
    float inv = 1.f / (float)(cnt > 1 ? cnt : 1);
    for (int k = threadIdx.x; k < C; k += blockDim.x) p[k] = pooled[g * C + k] * inv;
    __syncthreads();
    if (threadIdx.x < 49) {
        float acc = bl1[threadIdx.x];
        for (int k = 0; k < C; ++k) acc += p[k] * Wl1[k * 49 + threadIdx.x];
        t1[threadIdx.x] = acc;
    }
    __syncthreads();
    if (threadIdx.x < 2) {
        float acc = bl2[threadIdx.x];
        for (int k = 0; k < 49; ++k) acc += t1[k] * Wl2[k * 2 + threadIdx.x];
        out[g * 2 + threadIdx.x] = acc;
    }
}

// ---------------- launch ----------------

extern "C" void kernel_launch(void* const* d_in, const int* in_sizes, int n_in,
                              void* d_out, int out_size, void* d_ws, size_t ws_size,
                              hipStream_t stream) {
    const float* x     = (const float*)d_in[0];
    const int*   ei    = (const int*)d_in[1];
    const int*   batch = (const int*)d_in[2];
    const float* bn0g = (const float*)d_in[3];
    const float* bn0b = (const float*)d_in[4];
    const float* bn1g = (const float*)d_in[5];
    const float* bn1b = (const float*)d_in[6];
    const float* bn2g = (const float*)d_in[7];
    const float* bn2b = (const float*)d_in[8];
    const float* W1  = (const float*)d_in[9];
    const float* b1  = (const float*)d_in[10];
    const float* W2  = (const float*)d_in[11];
    const float* b2  = (const float*)d_in[12];
    const float* W3  = (const float*)d_in[13];
    const float* b3  = (const float*)d_in[14];
    const float* Wl1 = (const float*)d_in[15];
    const float* bl1 = (const float*)d_in[16];
    const float* Wl2 = (const float*)d_in[17];
    const float* bl2 = (const float*)d_in[18];

    const int N = in_sizes[0] / 7;
    const int E = in_sizes[1] / 2;
    const int EN = E + N;
    const int G = out_size / 2;
    const int NB = (N + 255) / 256;

    const int SP1 = 72, SP2 = 136, SP3 = 200;

    const int* src = ei;
    const int* dst = ei + E;

    char* w = (char*)d_ws;
    auto alloc = [&](size_t bytes) -> void* {
        void* p = (void*)w;
        w += ((bytes + 255) / 256) * 256;
        return p;
    };
    __half* bufH = (__half*)alloc((size_t)N * SP3 * sizeof(__half));
    __half* bufG = (__half*)alloc((size_t)N * SP2 * sizeof(__half));
    f16*    wp   = (f16*)  alloc((size_t)256 * 160 * sizeof(f16));
    float*  wrow = (float*)alloc(256 * sizeof(float));
    float* xp    = (float*)alloc((size_t)N * 8 * sizeof(float));
    float* disq  = (float*)alloc((size_t)N * sizeof(float));
    float* rsum  = (float*)alloc((size_t)N * sizeof(float));
    int*   deg   = (int*)  alloc((size_t)N * sizeof(int));
    int*   rs    = (int*)  alloc((size_t)N * sizeof(int));
    int*   cur   = (int*)  alloc((size_t)N * sizeof(int));
    int*   csr_s = (int*)  alloc((size_t)EN * sizeof(int));
    float* colsum0 = (float*)alloc(256 * sizeof(float));
    float* colsq0  = (float*)alloc(256 * sizeof(float));
    float* colsumA = (float*)alloc(256 * sizeof(float));
    float* colsqA  = (float*)alloc(256 * sizeof(float));
    float* colsumB = (float*)alloc(256 * sizeof(float));
    float* colsqB  = (float*)alloc(256 * sizeof(float));
    float* scale = (float*)alloc(256 * sizeof(float));
    float* shift = (float*)alloc(256 * sizeof(float));
    float* pooled= (float*)alloc((size_t)G * 199 * sizeof(float));
    int*   gstart= (int*)  alloc((size_t)G * sizeof(int));
    int*   gend  = (int*)  alloc((size_t)G * sizeof(int));
    int*   bsum  = (int*)  alloc((size_t)NB * sizeof(int));
    int*   boff  = (int*)  alloc((size_t)NB * sizeof(int));

    hipMemsetAsync(deg, 0, (size_t)N * sizeof(int), stream);
    hipMemsetAsync(colsum0, 0, 6 * 256 * sizeof(float), stream);
    hipMemsetAsync(pooled, 0, (size_t)G * 199 * sizeof(float), stream);
    hipMemsetAsync(gstart, 0, G * sizeof(int), stream);
    hipMemsetAsync(gend, 0, G * sizeof(int), stream);

    // ---- degree + CSR ----
    k_count<<<(EN + 255) / 256, 256, 0, stream>>>(dst, E, N, deg);
    k_disqrt<<<(N + 255) / 256, 256, 0, stream>>>(deg, disq, N);
    k_scan1<<<NB, 256, 0, stream>>>(deg, N, rs, bsum);
    k_scan2<<<1, 1, 0, stream>>>(bsum, NB, boff);
    k_scan3<<<NB, 256, 0, stream>>>(deg, rs, boff, N, rs, cur);
    k_fill<<<(EN + 255) / 256, 256, 0, stream>>>(src, dst, E, N, cur, csr_s);

    const int GB = (N + 127) / 128;
    const int GW = (N + 3) / 4;   // gather_split grid (4 waves/block, 1 node/wave)

    // ---- layer 1 ----
    k_bnstats<<<NB, 256, 0, stream>>>(x, N, 7, 7, colsum0, colsq0);
    k_bnfinal<<<1, 256, 0, stream>>>(colsum0, colsq0, bn0g, bn0b, 7, 1.f / (float)N, scale, shift);
    k_prepw<<<(128 * 32 + 255) / 256, 256, 0, stream>>>(W1, scale, wp, 7, 71, 32, 128);
    k_wrow<<<1, 128, 0, stream>>>(W1, shift, wrow, 7, 71, 128);
    k_padx<<<(N + 255) / 256, 256, 0, stream>>>(x, xp, N);
    k_gather8<<<(N + 255) / 256, 256, 0, stream>>>(xp, csr_s, disq, rs, deg, bufG, rsum, N);
    {
        dim3 grid(GB, 2);
        k_gemm_mfma<<<grid, 256, 0, stream>>>((const f16*)bufG, 8, wp, 32, rsum, wrow, b1,
                                              (f16*)bufH, SP1, colsumA, colsqA, 1, N, 71);
    }
    // ---- layer 2 ----
    k_bnfinal<<<1, 256, 0, stream>>>(colsumA, colsqA, bn1g, bn1b, 71, 1.f / (float)N, scale, shift);
    k_prepw<<<(192 * 96 + 255) / 256, 256, 0, stream>>>(W2, scale, wp, 71, 135, 96, 192);
    k_wrow<<<1, 192, 0, stream>>>(W2, shift, wrow, 71, 135, 192);
    // SP1=72 halfs: 9 float4 chunks, 7 groups -> 63 lanes
    k_gather_split<<<GW, 256, 0, stream>>>(bufH, SP1, 9, 7, rs, deg, csr_s, disq, bufG, N);
    {
        dim3 grid(GB, 3);
        k_gemm_mfma<<<grid, 256, 0, stream>>>((const f16*)bufG, SP1, wp, 96, rsum, wrow, b2,
                                              (f16*)bufH, SP2, colsumB, colsqB, 1, N, 135);
    }
    // ---- layer 3 ----
    k_bnfinal<<<1, 256, 0, stream>>>(colsumB, colsqB, bn2g, bn2b, 135, 1.f / (float)N, scale, shift);
    k_prepw<<<(256 * 160 + 255) / 256, 256, 0, stream>>>(W3, scale, wp, 135, 199, 160, 256);
    k_wrow<<<1, 256, 0, stream>>>(W3, shift, wrow, 135, 199, 256);
    // SP2=136 halfs: 17 float4 chunks, 3 groups -> 51 lanes
    k_gather_split<<<GW, 256, 0, stream>>>(bufH, SP2, 17, 3, rs, deg, csr_s, disq, bufG, N);
    {
        dim3 grid(GB, 4);
        k_gemm_mfma<<<grid, 256, 0, stream>>>((const f16*)bufG, SP2, wp, 160, rsum, wrow, b3,
                                              (f16*)bufH, SP3, colsumB, colsqB, 0, N, 199);
    }

    // ---- pool + head ----
    k_pool_h<<<NB, 256, 0, stream>>>(bufH, SP3, batch, N, 199, pooled);
    k_bounds<<<(N + 255) / 256, 256, 0, stream>>>(batch, N, gstart, gend);
    k_mlp<<<G, 64, 0, stream>>>(pooled, gstart, gend, Wl1, bl1, Wl2, bl2, (float*)d_out, 199);
}

// Round 8
// 710.912 us; speedup vs baseline: 1.1606x; 1.1606x over previous
//
#include <hip/hip_runtime.h>
#include <hip/hip_fp16.h>

#define EPSV 1e-5f
#define BIN_CH 4096

typedef _Float16 f16;
typedef f16 half8 __attribute__((ext_vector_type(8)));
typedef float f32x4 __attribute__((ext_vector_type(4)));

// ---------------- binned CSR construction ----------------
// Buckets of 256 nodes by dst. Phase 1: per-bucket totals. Phase 2: bin edges
// (packed src | dloc<<24) into contiguous bucket regions with per-block
// reserved runs (coalesced-ish writes). Phase 3: per-bucket local counting
// sort -> deg, rs, csr_s (scatter confined to <=20KB region, L2-absorbed).

__global__ __launch_bounds__(256) void k_btot(const int* __restrict__ dst, int E, int EN,
                                              int NBK, int* __restrict__ tot) {
    __shared__ int cnt[512];
    for (int b = threadIdx.x; b < 512; b += 256) cnt[b] = 0;
    __syncthreads();
    int i0 = blockIdx.x * BIN_CH;
    int i1 = i0 + BIN_CH; if (i1 > EN) i1 = EN;
    for (int i = i0 + threadIdx.x; i < i1; i += 256) {
        int d = (i < E) ? dst[i] : (i - E);
        atomicAdd(&cnt[d >> 8], 1);
    }
    __syncthreads();
    for (int b = threadIdx.x; b < NBK; b += 256)
        if (cnt[b]) atomicAdd(&tot[b], cnt[b]);
}

__global__ void k_breserve(const int* __restrict__ tot, int NBK,
                           int* __restrict__ bbase, int* __restrict__ gcur) {
    if (threadIdx.x == 0 && blockIdx.x == 0) {
        int run = 0;
        for (int b = 0; b < NBK; ++b) { bbase[b] = run; gcur[b] = run; run += tot[b]; }
    }
}

__global__ __launch_bounds__(256) void k_bin(const int* __restrict__ src,
                                             const int* __restrict__ dst, int E, int EN,
                                             int NBK, int* __restrict__ gcur,
                                             int* __restrict__ binned) {
    __shared__ int cnt[512];
    __shared__ int base[512];
    for (int b = threadIdx.x; b < 512; b += 256) cnt[b] = 0;
    __syncthreads();
    int i0 = blockIdx.x * BIN_CH;
    int i1 = i0 + BIN_CH; if (i1 > EN) i1 = EN;
    for (int i = i0 + threadIdx.x; i < i1; i += 256) {
        int d = (i < E) ? dst[i] : (i - E);
        atomicAdd(&cnt[d >> 8], 1);
    }
    __syncthreads();
    for (int b = threadIdx.x; b < NBK; b += 256)
        if (cnt[b]) base[b] = atomicAdd(&gcur[b], cnt[b]);
    __syncthreads();
    for (int i = i0 + threadIdx.x; i < i1; i += 256) {
        int s, d;
        if (i < E) { s = src[i]; d = dst[i]; }
        else       { s = i - E; d = s; }
        int pos = atomicAdd(&base[d >> 8], 1);
        binned[pos] = s | ((d & 255) << 24);   // src < 2^24
    }
}

__global__ __launch_bounds__(256) void k_bucket(const int* __restrict__ binned,
                                                const int* __restrict__ bbase,
                                                const int* __restrict__ tot, int N,
                                                int* __restrict__ deg, int* __restrict__ rs,
                                                int* __restrict__ csr_s) {
    __shared__ int deg_l[256];
    __shared__ int sc[256];
    __shared__ int cur_l[256];
    int b = blockIdx.x;
    int t = threadIdx.x;
    int start = bbase[b], end = start + tot[b];
    deg_l[t] = 0;
    __syncthreads();
    for (int i = start + t; i < end; i += 256)
        atomicAdd(&deg_l[((unsigned)binned[i]) >> 24], 1);
    __syncthreads();
    sc[t] = deg_l[t];
    __syncthreads();
    for (int off = 1; off < 256; off <<= 1) {
        int v = (t >= off) ? sc[t - off] : 0;
        __syncthreads();
        sc[t] += v;
        __syncthreads();
    }
    int rs_l = sc[t] - deg_l[t];
    int n = b * 256 + t;
    if (n < N) { deg[n] = deg_l[t]; rs[n] = start + rs_l; }
    cur_l[t] = start + rs_l;
    __syncthreads();
    for (int i = start + t; i < end; i += 256) {
        int p = binned[i];
        int loc = ((unsigned)p) >> 24;
        int idx = atomicAdd(&cur_l[loc], 1);
        csr_s[idx] = p & 0xFFFFFF;
    }
}

__global__ void k_disqrt(const int* __restrict__ deg, float* __restrict__ disq, int N) {
    int n = blockIdx.x * blockDim.x + threadIdx.x;
    if (n < N) disq[n] = rsqrtf((float)deg[n]);
}

// wave per node: csr_w[e] = disq[csr_s[e]] * disq[n]  (coalesced read/write)
__global__ __launch_bounds__(256) void k_wfill(const int* __restrict__ rs,
                                               const int* __restrict__ deg,
                                               const int* __restrict__ csr_s,
                                               const float* __restrict__ disq,
                                               float* __restrict__ csr_w, int N) {
    int wave = threadIdx.x >> 6, lane = threadIdx.x & 63;
    int n = blockIdx.x * 4 + wave;
    if (n >= N) return;
    int e0 = rs[n], dg = deg[n];
    float dn = disq[n];
    for (int j = lane; j < dg; j += 64) {
        int s = csr_s[e0 + j];
        csr_w[e0 + j] = disq[s] * dn;
    }
}

// ---------------- BN stats for layer 0 input x (width 7) ----------------

__global__ void k_bnstats(const float* __restrict__ H, int N, int C, int SP,
                          float* __restrict__ colsum, float* __restrict__ colsq) {
    int j = threadIdx.x;
    if (j >= C) return;
    int r0 = blockIdx.x * 256;
    int rend = r0 + 256; if (rend > N) rend = N;
    float s = 0.f, q = 0.f;
    for (int r = r0; r < rend; ++r) {
        float v = H[(size_t)r * SP + j];
        s += v;
        q += v * v;
    }
    atomicAdd(&colsum[j], s);
    atomicAdd(&colsq[j], q);
}

__global__ void k_bnfinal(const float* __restrict__ colsum, const float* __restrict__ colsq,
                          const float* __restrict__ g, const float* __restrict__ b,
                          int C, float invN,
                          float* __restrict__ scale, float* __restrict__ shift) {
    int i = threadIdx.x;
    if (i < C) {
        float m = colsum[i] * invN;
        float v = colsq[i] * invN - m * m;
        float rstd = rsqrtf(fmaxf(v, 0.f) + EPSV);
        float sc = rstd * g[i];
        scale[i] = sc;
        shift[i] = b[i] - m * sc;
    }
}

// ---- per-layer weight prep ----

__global__ void k_prepw(const float* __restrict__ W, const float* __restrict__ scale,
                        f16* __restrict__ Wp, int Cin, int Cout, int KP, int NP) {
    int idx = blockIdx.x * blockDim.x + threadIdx.x;
    if (idx >= NP * KP) return;
    int n = idx / KP;
    int k = idx - n * KP;
    float v = 0.f;
    if (k < Cin && n < Cout) v = scale[k] * W[(size_t)k * Cout + n];
    Wp[idx] = (f16)v;
}

__global__ void k_wrow(const float* __restrict__ W, const float* __restrict__ shift,
                       float* __restrict__ wrow, int Cin, int Cout, int NP) {
    int c = blockIdx.x * blockDim.x + threadIdx.x;
    if (c >= NP) return;
    float acc = 0.f;
    if (c < Cout)
        for (int k = 0; k < Cin; ++k) acc += shift[k] * W[(size_t)k * Cout + c];
    wrow[c] = acc;
}

// ---------------- pad x [N,7] -> xp [N,8] fp32 ----------------

__global__ void k_padx(const float* __restrict__ x, float* __restrict__ xp, int N) {
    int n = blockIdx.x * blockDim.x + threadIdx.x;
    if (n >= N) return;
    float4 a, b;
    a.x = x[(size_t)n * 7 + 0]; a.y = x[(size_t)n * 7 + 1];
    a.z = x[(size_t)n * 7 + 2]; a.w = x[(size_t)n * 7 + 3];
    b.x = x[(size_t)n * 7 + 4]; b.y = x[(size_t)n * 7 + 5];
    b.z = x[(size_t)n * 7 + 6]; b.w = 0.f;
    *(float4*)(xp + (size_t)n * 8) = a;
    *(float4*)(xp + (size_t)n * 8 + 4) = b;
}

// ---------------- gathers: G = S . X ----------------

// width-8 fp32 input; emits rsum[n] = sum_e w_e
__global__ void k_gather8(const float* __restrict__ xp, const int* __restrict__ csr_s,
                          const float* __restrict__ csr_w,
                          const int* __restrict__ rs, const int* __restrict__ deg,
                          __half* __restrict__ out, float* __restrict__ rsum, int N) {
    int n = blockIdx.x * blockDim.x + threadIdx.x;
    if (n >= N) return;
    int e0 = rs[n], eend = e0 + deg[n];
    float a0 = 0.f, a1 = 0.f, a2 = 0.f, a3 = 0.f, a4 = 0.f, a5 = 0.f, a6 = 0.f, a7 = 0.f;
    float ws = 0.f;
    for (int e = e0; e < eend; ++e) {
        int s = csr_s[e];
        float w = csr_w[e];
        ws += w;
        float4 r0 = *(const float4*)(xp + (size_t)s * 8);
        float4 r1 = *(const float4*)(xp + (size_t)s * 8 + 4);
        a0 = fmaf(w, r0.x, a0); a1 = fmaf(w, r0.y, a1);
        a2 = fmaf(w, r0.z, a2); a3 = fmaf(w, r0.w, a3);
        a4 = fmaf(w, r1.x, a4); a5 = fmaf(w, r1.y, a5);
        a6 = fmaf(w, r1.z, a6); a7 = fmaf(w, r1.w, a7);
    }
    rsum[n] = ws;
    __half h[8];
    h[0] = __float2half(a0); h[1] = __float2half(a1);
    h[2] = __float2half(a2); h[3] = __float2half(a3);
    h[4] = __float2half(a4); h[5] = __float2half(a5);
    h[6] = __float2half(a6); h[7] = __float2half(a7);
    *(float4*)(out + (size_t)n * 8) = *(float4*)h;
}

// generic fp16 gather; npw nodes per wave (1 or 2), 4 halfs per lane
__global__ __launch_bounds__(256) void k_gather_h(
    const __half* __restrict__ A, int SPh, int CH,
    const int* __restrict__ rs, const int* __restrict__ deg,
    const int* __restrict__ csr_s, const float* __restrict__ csr_w,
    __half* __restrict__ out, int N, int npw) {
    int wave = threadIdx.x >> 6;
    int lane = threadIdx.x & 63;
    int sub, lsub;
    if (npw == 2) { sub = lane >> 5; lsub = lane & 31; }
    else          { sub = 0;         lsub = lane; }
    int n = (blockIdx.x * 4 + wave) * npw + sub;
    if (n >= N) return;
    int c0 = lsub * 4;
    bool active = lsub < CH;
    int cc = active ? c0 : 0;

    int e0 = rs[n];
    int eend = e0 + deg[n];
    float acc0 = 0.f, acc1 = 0.f, acc2 = 0.f, acc3 = 0.f;

    int e = e0;
    for (; e + 4 <= eend; e += 4) {
        int s0 = csr_s[e + 0], s1 = csr_s[e + 1], s2 = csr_s[e + 2], s3 = csr_s[e + 3];
        float w0 = csr_w[e + 0], w1 = csr_w[e + 1], w2 = csr_w[e + 2], w3 = csr_w[e + 3];
        float2 r0 = *(const float2*)(A + (size_t)s0 * SPh + cc);
        float2 r1 = *(const float2*)(A + (size_t)s1 * SPh + cc);
        float2 r2 = *(const float2*)(A + (size_t)s2 * SPh + cc);
        float2 r3 = *(const float2*)(A + (size_t)s3 * SPh + cc);
        {
            float2 f01 = __half22float2(((const __half2*)&r0)[0]);
            float2 f23 = __half22float2(((const __half2*)&r0)[1]);
            acc0 = fmaf(w0, f01.x, acc0); acc1 = fmaf(w0, f01.y, acc1);
            acc2 = fmaf(w0, f23.x, acc2); acc3 = fmaf(w0, f23.y, acc3);
        }
        {
            float2 f01 = __half22float2(((const __half2*)&r1)[0]);
            float2 f23 = __half22float2(((const __half2*)&r1)[1]);
            acc0 = fmaf(w1, f01.x, acc0); acc1 = fmaf(w1, f01.y, acc1);
            acc2 = fmaf(w1, f23.x, acc2); acc3 = fmaf(w1, f23.y, acc3);
        }
        {
            float2 f01 = __half22float2(((const __half2*)&r2)[0]);
            float2 f23 = __half22float2(((const __half2*)&r2)[1]);
            acc0 = fmaf(w2, f01.x, acc0); acc1 = fmaf(w2, f01.y, acc1);
            acc2 = fmaf(w2, f23.x, acc2); acc3 = fmaf(w2, f23.y, acc3);
        }
        {
            float2 f01 = __half22float2(((const __half2*)&r3)[0]);
            float2 f23 = __half22float2(((const __half2*)&r3)[1]);
            acc0 = fmaf(w3, f01.x, acc0); acc1 = fmaf(w3, f01.y, acc1);
            acc2 = fmaf(w3, f23.x, acc2); acc3 = fmaf(w3, f23.y, acc3);
        }
    }
    for (; e < eend; ++e) {
        int s = csr_s[e];
        float w = csr_w[e];
        float2 r = *(const float2*)(A + (size_t)s * SPh + cc);
        float2 f01 = __half22float2(((const __half2*)&r)[0]);
        float2 f23 = __half22float2(((const __half2*)&r)[1]);
        acc0 = fmaf(w, f01.x, acc0); acc1 = fmaf(w, f01.y, acc1);
        acc2 = fmaf(w, f23.x, acc2); acc3 = fmaf(w, f23.y, acc3);
    }

    if (active) {
        __half2 h01 = __floats2half2_rn(acc0, acc1);
        __half2 h23 = __floats2half2_rn(acc2, acc3);
        float2 packed;
        ((__half2*)&packed)[0] = h01;
        ((__half2*)&packed)[1] = h23;
        *(float2*)(out + (size_t)n * SPh + c0) = packed;
    }
}

// ------------- MFMA GEMM: H = relu(G @ Wp_t^T + rsum (x) wrow + bias) -------------

__global__ __launch_bounds__(256) void k_gemm_mfma(
    const f16* __restrict__ A, int SPa,
    const f16* __restrict__ Bt, int KP,
    const float* __restrict__ rsum, const float* __restrict__ wrow,
    const float* __restrict__ bias,
    f16* __restrict__ out, int SPo,
    float* __restrict__ colsum, float* __restrict__ colsq, int do_stats,
    int N, int Cout) {
    __shared__ f16 As[128][40];
    __shared__ float s_sum[64];
    __shared__ float s_sq[64];
    const int r0 = blockIdx.x * 128;
    const int c0 = blockIdx.y * 64;
    const int t = threadIdx.x;
    const int wave = t >> 6, lane = t & 63;
    const int l15 = lane & 15, quad = lane >> 4;

    if (t < 64) { s_sum[t] = 0.f; s_sq[t] = 0.f; }

    f32x4 zero4 = {0.f, 0.f, 0.f, 0.f};
    f32x4 acc[2][4];
#pragma unroll
    for (int mi = 0; mi < 2; ++mi)
#pragma unroll
        for (int ni = 0; ni < 4; ++ni) acc[mi][ni] = zero4;

    const int KT = KP >> 5;
    for (int kt = 0; kt < KT; ++kt) {
        int k0 = kt * 32;
        {
            int kcol = (t & 7) * 4;
            int rbase = t >> 3;
            int gk = k0 + kcol;
            bool kok = (gk + 4 <= SPa);
#pragma unroll
            for (int i = 0; i < 4; ++i) {
                int row = rbase + i * 32;
                int gr = r0 + row;
                ushort4 v = {0, 0, 0, 0};
                if (gr < N && kok)
                    v = *(const ushort4*)(A + (size_t)gr * SPa + gk);
                *(ushort4*)&As[row][kcol] = v;
            }
        }
        __syncthreads();
        half8 a0 = *(const half8*)&As[wave * 32 + l15][quad * 8];
        half8 a1 = *(const half8*)&As[wave * 32 + 16 + l15][quad * 8];
#pragma unroll
        for (int ni = 0; ni < 4; ++ni) {
            half8 b = *(const half8*)(Bt + (size_t)(c0 + ni * 16 + l15) * KP + k0 + quad * 8);
            acc[0][ni] = __builtin_amdgcn_mfma_f32_16x16x32_f16(a0, b, acc[0][ni], 0, 0, 0);
            acc[1][ni] = __builtin_amdgcn_mfma_f32_16x16x32_f16(a1, b, acc[1][ni], 0, 0, 0);
        }
        __syncthreads();
    }

    float wr[4], bi[4];
#pragma unroll
    for (int ni = 0; ni < 4; ++ni) {
        int gc = c0 + ni * 16 + l15;
        wr[ni] = wrow[gc];
        bi[ni] = (gc < Cout) ? bias[gc] : 0.f;
    }
    float ps[4] = {}, pq[4] = {};
#pragma unroll
    for (int mi = 0; mi < 2; ++mi) {
#pragma unroll
        for (int reg = 0; reg < 4; ++reg) {
            int gr = r0 + wave * 32 + mi * 16 + quad * 4 + reg;
            if (gr >= N) continue;
            float rsv = rsum[gr];
#pragma unroll
            for (int ni = 0; ni < 4; ++ni) {
                int gc = c0 + ni * 16 + l15;
                float o = acc[mi][ni][reg] + rsv * wr[ni] + bi[ni];
                o = fmaxf(o, 0.f);
                if (gc >= Cout) o = 0.f;
                ps[ni] += o; pq[ni] += o * o;
                if (gc < SPo) out[(size_t)gr * SPo + gc] = (f16)o;
            }
        }
    }
    if (do_stats) {
#pragma unroll
        for (int ni = 0; ni < 4; ++ni) {
            int cl = ni * 16 + l15;
            atomicAdd(&s_sum[cl], ps[ni]);
            atomicAdd(&s_sq[cl], pq[ni]);
        }
        __syncthreads();
        if (t < 64 && c0 + t < Cout) {
            atomicAdd(&colsum[c0 + t], s_sum[t]);
            atomicAdd(&colsq[c0 + t], s_sq[t]);
        }
    }
}

// ---------------- mean pool (fp16 input, batch is sorted) ----------------

__global__ void k_pool_h(const __half* __restrict__ H, int SP, const int* __restrict__ batch,
                         int N, int C, float* __restrict__ pooled) {
    __shared__ int sb[256];
    int r0 = blockIdx.x * 256;
    int rows = N - r0; if (rows > 256) rows = 256;
    if (threadIdx.x < rows) sb[threadIdx.x] = batch[r0 + threadIdx.x];
    __syncthreads();
    int c = threadIdx.x;
    if (c >= C) return;
    int cg = sb[0];
    float acc = 0.f;
    for (int r = 0; r < rows; ++r) {
        int g = sb[r];
        if (g != cg) { atomicAdd(&pooled[cg * C + c], acc); acc = 0.f; cg = g; }
        acc += __half2float(H[(size_t)(r0 + r) * SP + c]);
    }
    atomicAdd(&pooled[cg * C + c], acc);
}

__global__ void k_bounds(const int* __restrict__ batch, int N,
                         int* __restrict__ gstart, int* __restrict__ gend) {
    int n = blockIdx.x * blockDim.x + threadIdx.x;
    if (n >= N) return;
    int g = batch[n];
    if (n == 0 || batch[n - 1] != g) gstart[g] = n;
    if (n == N - 1 || batch[n + 1] != g) gend[g] = n + 1;
}

// ---------------- head MLP ----------------

__global__ void k_mlp(const float* __restrict__ pooled, const int* __restrict__ gstart,
                      const int* __restrict__ gend,
                      const float* __restrict__ Wl1, const float* __restrict__ bl1,
                      const float* __restrict__ Wl2, const float* __restrict__ bl2,
                      float* __restrict__ out, int C) {
    __shared__ float p[199];
    __shared__ float t1[49];
    int g = blockIdx.x;
    int cnt = gend[g] - gstart[g];
    float inv = 1.f / (float)(cnt > 1 ? cnt : 1);
    for (int k = threadIdx.x; k < C; k += blockDim.x) p[k] = pooled[g * C + k] * inv;
    __syncthreads();
    if (threadIdx.x < 49) {
        float acc = bl1[threadIdx.x];
        for (int k = 0; k < C; ++k) acc += p[k] * Wl1[k * 49 + threadIdx.x];
        t1[threadIdx.x] = acc;
    }
    __syncthreads();
    if (threadIdx.x < 2) {
        float acc = bl2[threadIdx.x];
        for (int k = 0; k < 49; ++k) acc += t1[k] * Wl2[k * 2 + threadIdx.x];
        out[g * 2 + threadIdx.x] = acc;
    }
}

// ---------------- launch ----------------

extern "C" void kernel_launch(void* const* d_in, const int* in_sizes, int n_in,
                              void* d_out, int out_size, void* d_ws, size_t ws_size,
                              hipStream_t stream) {
    const float* x     = (const float*)d_in[0];
    const int*   ei    = (const int*)d_in[1];
    const int*   batch = (const int*)d_in[2];
    const float* bn0g = (const float*)d_in[3];
    const float* bn0b = (const float*)d_in[4];
    const float* bn1g = (const float*)d_in[5];
    const float* bn1b = (const float*)d_in[6];
    const float* bn2g = (const float*)d_in[7];
    const float* bn2b = (const float*)d_in[8];
    const float* W1  = (const float*)d_in[9];
    const float* b1  = (const float*)d_in[10];
    const float* W2  = (const float*)d_in[11];
    const float* b2  = (const float*)d_in[12];
    const float* W3  = (const float*)d_in[13];
    const float* b3  = (const float*)d_in[14];
    const float* Wl1 = (const float*)d_in[15];
    const float* bl1 = (const float*)d_in[16];
    const float* Wl2 = (const float*)d_in[17];
    const float* bl2 = (const float*)d_in[18];

    const int N = in_sizes[0] / 7;
    const int E = in_sizes[1] / 2;
    const int EN = E + N;
    const int G = out_size / 2;
    const int NB = (N + 255) / 256;
    const int NBK = (N + 255) / 256;        // buckets of 256 nodes
    const int NBIN = (EN + BIN_CH - 1) / BIN_CH;

    const int SP1 = 72, SP2 = 136, SP3 = 200;

    const int* src = ei;
    const int* dst = ei + E;

    char* w = (char*)d_ws;
    auto alloc = [&](size_t bytes) -> void* {
        void* p = (void*)w;
        w += ((bytes + 255) / 256) * 256;
        return p;
    };
    __half* bufH = (__half*)alloc((size_t)N * SP3 * sizeof(__half));
    __half* bufG = (__half*)alloc((size_t)N * SP2 * sizeof(__half));
    f16*    wp   = (f16*)  alloc((size_t)256 * 160 * sizeof(f16));
    float*  wrow = (float*)alloc(256 * sizeof(float));
    float* xp    = (float*)alloc((size_t)N * 8 * sizeof(float));
    float* disq  = (float*)alloc((size_t)N * sizeof(float));
    float* rsum  = (float*)alloc((size_t)N * sizeof(float));
    int*   deg   = (int*)  alloc((size_t)N * sizeof(int));
    int*   rs    = (int*)  alloc((size_t)N * sizeof(int));
    int*   binned= (int*)  alloc((size_t)EN * sizeof(int));
    int*   csr_s = (int*)  alloc((size_t)EN * sizeof(int));
    float* csr_w = (float*)alloc((size_t)EN * sizeof(float));
    int*   tot   = (int*)  alloc(512 * sizeof(int));
    int*   bbase = (int*)  alloc(512 * sizeof(int));
    int*   gcur  = (int*)  alloc(512 * sizeof(int));
    float* colsum0 = (float*)alloc(256 * sizeof(float));
    float* colsq0  = (float*)alloc(256 * sizeof(float));
    float* colsumA = (float*)alloc(256 * sizeof(float));
    float* colsqA  = (float*)alloc(256 * sizeof(float));
    float* colsumB = (float*)alloc(256 * sizeof(float));
    float* colsqB  = (float*)alloc(256 * sizeof(float));
    float* scale = (float*)alloc(256 * sizeof(float));
    float* shift = (float*)alloc(256 * sizeof(float));
    float* pooled= (float*)alloc((size_t)G * 199 * sizeof(float));
    int*   gstart= (int*)  alloc((size_t)G * sizeof(int));
    int*   gend  = (int*)  alloc((size_t)G * sizeof(int));

    hipMemsetAsync(tot, 0, 512 * sizeof(int), stream);
    hipMemsetAsync(colsum0, 0, 6 * 256 * sizeof(float), stream);
    hipMemsetAsync(pooled, 0, (size_t)G * 199 * sizeof(float), stream);
    hipMemsetAsync(gstart, 0, G * sizeof(int), stream);
    hipMemsetAsync(gend, 0, G * sizeof(int), stream);

    // ---- binned CSR build ----
    k_btot<<<NBIN, 256, 0, stream>>>(dst, E, EN, NBK, tot);
    k_breserve<<<1, 1, 0, stream>>>(tot, NBK, bbase, gcur);
    k_bin<<<NBIN, 256, 0, stream>>>(src, dst, E, EN, NBK, gcur, binned);
    k_bucket<<<NBK, 256, 0, stream>>>(binned, bbase, tot, N, deg, rs, csr_s);
    k_disqrt<<<(N + 255) / 256, 256, 0, stream>>>(deg, disq, N);
    k_wfill<<<(N + 3) / 4, 256, 0, stream>>>(rs, deg, csr_s, disq, csr_w, N);

    const int GB = (N + 127) / 128;

    // ---- layer 1 ----
    k_bnstats<<<NB, 256, 0, stream>>>(x, N, 7, 7, colsum0, colsq0);
    k_bnfinal<<<1, 256, 0, stream>>>(colsum0, colsq0, bn0g, bn0b, 7, 1.f / (float)N, scale, shift);
    k_prepw<<<(128 * 32 + 255) / 256, 256, 0, stream>>>(W1, scale, wp, 7, 71, 32, 128);
    k_wrow<<<1, 128, 0, stream>>>(W1, shift, wrow, 7, 71, 128);
    k_padx<<<(N + 255) / 256, 256, 0, stream>>>(x, xp, N);
    k_gather8<<<(N + 255) / 256, 256, 0, stream>>>(xp, csr_s, csr_w, rs, deg, bufG, rsum, N);
    {
        dim3 grid(GB, 2);
        k_gemm_mfma<<<grid, 256, 0, stream>>>((const f16*)bufG, 8, wp, 32, rsum, wrow, b1,
                                              (f16*)bufH, SP1, colsumA, colsqA, 1, N, 71);
    }
    // ---- layer 2 ----
    k_bnfinal<<<1, 256, 0, stream>>>(colsumA, colsqA, bn1g, bn1b, 71, 1.f / (float)N, scale, shift);
    k_prepw<<<(192 * 96 + 255) / 256, 256, 0, stream>>>(W2, scale, wp, 71, 135, 96, 192);
    k_wrow<<<1, 192, 0, stream>>>(W2, shift, wrow, 71, 135, 192);
    k_gather_h<<<(N + 7) / 8, 256, 0, stream>>>(bufH, SP1, 18, rs, deg, csr_s, csr_w, bufG, N, 2);
    {
        dim3 grid(GB, 3);
        k_gemm_mfma<<<grid, 256, 0, stream>>>((const f16*)bufG, SP1, wp, 96, rsum, wrow, b2,
                                              (f16*)bufH, SP2, colsumB, colsqB, 1, N, 135);
    }
    // ---- layer 3 ----
    k_bnfinal<<<1, 256, 0, stream>>>(colsumB, colsqB, bn2g, bn2b, 135, 1.f / (float)N, scale, shift);
    k_prepw<<<(256 * 160 + 255) / 256, 256, 0, stream>>>(W3, scale, wp, 135, 199, 160, 256);
    k_wrow<<<1, 256, 0, stream>>>(W3, shift, wrow, 135, 199, 256);
    k_gather_h<<<(N + 3) / 4, 256, 0, stream>>>(bufH, SP2, 34, rs, deg, csr_s, csr_w, bufG, N, 1);
    {
        dim3 grid(GB, 4);
        k_gemm_mfma<<<grid, 256, 0, stream>>>((const f16*)bufG, SP2, wp, 160, rsum, wrow, b3,
                                              (f16*)bufH, SP3, colsumB, colsqB, 0, N, 199);
    }

    // ---- pool + head ----
    k_pool_h<<<NB, 256, 0, stream>>>(bufH, SP3, batch, N, 199, pooled);
    k_bounds<<<(N + 255) / 256, 256, 0, stream>>>(batch, N, gstart, gend);
    k_mlp<<<G, 64, 0, stream>>>(pooled, gstart, gend, Wl1, bl1, Wl2, bl2, (float*)d_out, 199);
}